// Round 2
// baseline (1340.732 us; speedup 1.0000x reference)
//
#include <hip/hip_runtime.h>

typedef _Float16 h8_t __attribute__((ext_vector_type(8)));
typedef _Float16 h4_t __attribute__((ext_vector_type(4)));
typedef float f4_t __attribute__((ext_vector_type(4)));

#define MFMA16(a, b, c) __builtin_amdgcn_mfma_f32_16x16x32_f16((a), (b), (c), 0, 0, 0)

// async global->LDS DMA, 16B per lane; LDS dest must be wave-uniform base + lane*16
__device__ inline void gl_lds16(const _Float16* g, _Float16* l) {
    __builtin_amdgcn_global_load_lds(
        (const __attribute__((address_space(1))) unsigned int*)g,
        (__attribute__((address_space(3))) unsigned int*)l, 16, 0, 0);
}

// ---------------------------------------------------------------------------
// W [K=1024][N=1024] f32  ->  Wt [N][K] f16   (tiled transpose)
__global__ void wtrans(const float* __restrict__ W, _Float16* __restrict__ Wt) {
    __shared__ float tile[32][33];
    int tid = threadIdx.x;
    int tx = tid & 31, ty = tid >> 5;
    int nb = blockIdx.x * 32, kb = blockIdx.y * 32;
    for (int p = 0; p < 4; ++p)
        tile[ty + p * 8][tx] = W[(size_t)(kb + ty + p * 8) * 1024 + nb + tx];
    __syncthreads();
    for (int p = 0; p < 4; ++p)
        Wt[(size_t)(nb + ty + p * 8) * 1024 + kb + tx] = (_Float16)tile[tx][ty + p * 8];
}

// ---------------------------------------------------------------------------
// Projection GEMM. A-operand read directly from f32 activations (reg-staged +
// cvt), B-operand (pre-transposed f16 weights) staged via global_load_lds.
// Out = (X @ Wt^T + bias) * scale.
// vmode==0: Out [b][h][s][64] ; vmode==1: Out [b][h][64][s] (V transposed)
__global__ __launch_bounds__(256, 2) void proj_gemm(
    const float* __restrict__ X, const _Float16* __restrict__ Wt,
    const float* __restrict__ bias, _Float16* __restrict__ Out,
    float scale, int vmode)
{
    __shared__ __align__(16) _Float16 Asm[128 * 32];
    __shared__ __align__(16) _Float16 Bsm[128 * 32];
    int tid = threadIdx.x;
    int wave = tid >> 6, lane = tid & 63;
    int l15 = lane & 15, quad = lane >> 4;
    int m0 = blockIdx.x * 128, n0 = blockIdx.y * 128;
    int wm = (wave >> 1) * 64, wn = (wave & 1) * 64;
    f4_t acc[4][4] = {};
    int f0 = wave * 128 + lane;

    for (int kt = 0; kt < 1024; kt += 32) {
        #pragma unroll
        for (int j = 0; j < 2; ++j) {
            int f = f0 + j * 64;
            int r = f >> 2, c = (f & 3) * 8;
            gl_lds16(&Wt[(size_t)(n0 + r) * 1024 + kt + c], &Bsm[f * 8]);
        }
        #pragma unroll
        for (int j = 0; j < 2; ++j) {
            int f = f0 + j * 64;
            int r = f >> 2, c = (f & 3) * 8;
            const float* xp = &X[(size_t)(m0 + r) * 1024 + kt + c];
            f4_t x0 = *(const f4_t*)xp;
            f4_t x1 = *(const f4_t*)(xp + 4);
            h8_t h;
            #pragma unroll
            for (int i = 0; i < 4; ++i) { h[i] = (_Float16)x0[i]; h[4 + i] = (_Float16)x1[i]; }
            *(h8_t*)&Asm[f * 8] = h;
        }
        __syncthreads();  // drains vmcnt(0) (B staging) + lgkm (A ds_writes)
        h8_t af[4], bf[4];
        #pragma unroll
        for (int i = 0; i < 4; ++i) af[i] = *(const h8_t*)&Asm[(wm + i * 16 + l15) * 32 + quad * 8];
        #pragma unroll
        for (int j = 0; j < 4; ++j) bf[j] = *(const h8_t*)&Bsm[(wn + j * 16 + l15) * 32 + quad * 8];
        #pragma unroll
        for (int i = 0; i < 4; ++i)
            #pragma unroll
            for (int j = 0; j < 4; ++j)
                acc[i][j] = MFMA16(af[i], bf[j], acc[i][j]);
        __syncthreads();
    }
    #pragma unroll
    for (int j = 0; j < 4; ++j) {
        int n = n0 + wn + j * 16 + l15;
        float bv = bias[n];
        int h = n >> 6, d = n & 63;
        #pragma unroll
        for (int i = 0; i < 4; ++i) {
            #pragma unroll
            for (int r = 0; r < 4; ++r) {
                int m = m0 + wm + i * 16 + quad * 4 + r;
                int bb = m >> 10, ss = m & 1023;
                float v = (acc[i][j][r] + bv) * scale;
                size_t oidx = vmode ? (((size_t)(bb * 16 + h) * 64 + d) * 1024 + ss)
                                    : (((size_t)(bb * 16 + h) * 1024 + ss) * 64 + d);
                Out[oidx] = (_Float16)v;
            }
        }
    }
}

// ---------------------------------------------------------------------------
// rel B-operand loader, f32 -> h8 fragment
__device__ inline h8_t ld_rel32(const float* __restrict__ relf, size_t idx) {
    f4_t a = *(const f4_t*)(relf + idx);
    f4_t b = *(const f4_t*)(relf + idx + 4);
    h8_t h;
    #pragma unroll
    for (int j = 0; j < 4; ++j) { h[j] = (_Float16)a[j]; h[4 + j] = (_Float16)b[j]; }
    return h;
}

// ---------------------------------------------------------------------------
// Fused attention, split-K flash style. Grid (64 q-blocks, 8 batches, 2 k-halves).
// Each WG: 16 q-rows x all 16 heads x 512 keys; writes UNNORMALIZED partial
// O^T + per-row (m, l). A combine kernel merges the two halves.
// Round-0 proven structure otherwise: scores transposed D[t][q] (softmax rows
// in lane dim l15=q), Kh pre-scaled 1/8, rel added unscaled.
// LDS = 19584 (R, single-buffered) + 20480 (P, wave-private) = 40064 B
// -> 4 WGs/CU; launch_bounds(256,4) pins VGPR<=128 -> 16 waves/CU.
__global__ __launch_bounds__(256, 4) void attn_kernel(
    const _Float16* __restrict__ Qh,   // [B][H][S][64]
    const _Float16* __restrict__ Kh,   // [B][H][S][64], pre-scaled 1/8
    const _Float16* __restrict__ Vt,   // [B][H][64][S]
    const float* __restrict__ relf,    // [S][S][64] f32
    const int* __restrict__ mask,      // [B][S][S] int32 (nonzero = masked)
    float* __restrict__ out0,          // z=0 partial (final out buffer)
    float* __restrict__ out1,          // z=1 partial (workspace)
    float* __restrict__ mpart,         // [2][B][H][S]
    float* __restrict__ lpart)         // [2][B][H][S]
{
    __shared__ __align__(16) _Float16 R_lds[16][17][36]; // [q_local][g][t]
    __shared__ __align__(16) _Float16 P_lds[16][16][40]; // [g][q_local][t] (wave-private)

    const int tid = threadIdx.x;
    const int wave = tid >> 6, lane = tid & 63;
    const int l15 = lane & 15, quad = lane >> 4;
    const int b = blockIdx.y;
    const int q0 = blockIdx.x * 16;
    const int kz = blockIdx.z;
    const int tbase = kz * 512;

    // persistent B-operand fragments of Q
    h8_t bQ[4][2]; // QK: B[d][q] for wave's 4 heads g
    h8_t bR[4][2]; // rel: B[d][g] for wave's 4 queries q
    #pragma unroll
    for (int gi = 0; gi < 4; ++gi) {
        int g = wave * 4 + gi;
        const _Float16* qp = Qh + ((size_t)(b * 16 + g) * 1024 + q0 + l15) * 64 + quad * 8;
        bQ[gi][0] = *(const h8_t*)qp;
        bQ[gi][1] = *(const h8_t*)(qp + 32);
    }
    #pragma unroll
    for (int qi = 0; qi < 4; ++qi) {
        int q = q0 + wave * 4 + qi;
        const _Float16* qp = Qh + ((size_t)(b * 16 + l15) * 1024 + q) * 64 + quad * 8;
        bR[qi][0] = *(const h8_t*)qp;
        bR[qi][1] = *(const h8_t*)(qp + 32);
    }

    f4_t acc[4][4] = {}; // [gi][dm] O^T frags: rows d, cols q
    float mst[4], lst[4];
    #pragma unroll
    for (int gi = 0; gi < 4; ++gi) { mst[gi] = -1e30f; lst[gi] = 0.0f; }

    for (int it = 0; it < 16; ++it) {
        const int t0 = tbase + it * 32;

        // mask bits for this lane's q row (independent — issue first)
        const int* mrow = &mask[((size_t)b * 1024 + q0 + l15) * 1024 + t0];
        int4 mk0 = *(const int4*)(mrow + quad * 4);
        int4 mk1 = *(const int4*)(mrow + 16 + quad * 4);

        // ---- rel batch: 16 independent 32B streams issued before any consumer
        h8_t relv[4][2][2];
        #pragma unroll
        for (int qi = 0; qi < 4; ++qi) {
            size_t rb = ((size_t)(q0 + wave * 4 + qi) * 1024 + t0 + l15) * 64 + quad * 8;
            relv[qi][0][0] = ld_rel32(relf, rb);
            relv[qi][0][1] = ld_rel32(relf, rb + 32);
            relv[qi][1][0] = ld_rel32(relf, rb + 1024);
            relv[qi][1][1] = ld_rel32(relf, rb + 1056);
        }
        // ---- Phase A: rel GEMMs, D[t][g] per owned q -> R_lds
        #pragma unroll
        for (int qi = 0; qi < 4; ++qi) {
            #pragma unroll
            for (int tm = 0; tm < 2; ++tm) {
                f4_t c = {0.f, 0.f, 0.f, 0.f};
                c = MFMA16(relv[qi][tm][0], bR[qi][0], c);
                c = MFMA16(relv[qi][tm][1], bR[qi][1], c);
                h4_t h;
                #pragma unroll
                for (int r = 0; r < 4; ++r) h[r] = (_Float16)c[r];
                *(h4_t*)&R_lds[wave * 4 + qi][l15][tm * 16 + quad * 4] = h;
            }
        }

        // ---- K batch: issued pre-barrier so latency drains during barrier
        h8_t kv[4][2][2];
        #pragma unroll
        for (int gi = 0; gi < 4; ++gi) {
            const _Float16* kp =
                Kh + ((size_t)(b * 16 + wave * 4 + gi) * 1024 + t0 + l15) * 64 + quad * 8;
            kv[gi][0][0] = *(const h8_t*)kp;
            kv[gi][0][1] = *(const h8_t*)(kp + 32);
            kv[gi][1][0] = *(const h8_t*)(kp + 1024);
            kv[gi][1][1] = *(const h8_t*)(kp + 1056);
        }
        __syncthreads(); // R_lds visible to all waves

        int mm[8] = {mk0.x, mk0.y, mk0.z, mk0.w, mk1.x, mk1.y, mk1.z, mk1.w};

        // ---- Phase B: QK^T (transposed) + online softmax, all in registers
        #pragma unroll
        for (int gi = 0; gi < 4; ++gi) {
            int g = wave * 4 + gi;
            f4_t s[2];
            #pragma unroll
            for (int tm = 0; tm < 2; ++tm) {
                h4_t rh = *(const h4_t*)&R_lds[l15][g][tm * 16 + quad * 4];
                f4_t c;
                #pragma unroll
                for (int r = 0; r < 4; ++r) c[r] = (float)rh[r];
                c = MFMA16(kv[gi][tm][0], bQ[gi][0], c);
                c = MFMA16(kv[gi][tm][1], bQ[gi][1], c);
                s[tm] = c;
            }
            #pragma unroll
            for (int tm = 0; tm < 2; ++tm)
                #pragma unroll
                for (int r = 0; r < 4; ++r)
                    if (mm[tm * 4 + r]) s[tm][r] = -1e8f;

            float mx = s[0][0];
            #pragma unroll
            for (int tm = 0; tm < 2; ++tm)
                #pragma unroll
                for (int r = 0; r < 4; ++r) mx = fmaxf(mx, s[tm][r]);
            mx = fmaxf(mx, __shfl_xor(mx, 16));
            mx = fmaxf(mx, __shfl_xor(mx, 32));
            float mnew = fmaxf(mst[gi], mx);
            float alpha = __expf(mst[gi] - mnew);
            mst[gi] = mnew;
            float rs = 0.0f;
            #pragma unroll
            for (int tm = 0; tm < 2; ++tm)
                #pragma unroll
                for (int r = 0; r < 4; ++r) {
                    float p = __expf(s[tm][r] - mnew);
                    s[tm][r] = p;
                    rs += p;
                }
            rs += __shfl_xor(rs, 16);
            rs += __shfl_xor(rs, 32);
            lst[gi] = lst[gi] * alpha + rs;
            #pragma unroll
            for (int dm = 0; dm < 4; ++dm) acc[gi][dm] *= alpha; // alpha uniform per lane (q=l15)
            #pragma unroll
            for (int tm = 0; tm < 2; ++tm) {
                h4_t h;
                #pragma unroll
                for (int r = 0; r < 4; ++r) h[r] = (_Float16)s[tm][r];
                *(h4_t*)&P_lds[g][l15][tm * 16 + quad * 4] = h;
            }
        }

        // ---- V batch (kv regs dead by now)
        h8_t vv[4][4];
        #pragma unroll
        for (int gi = 0; gi < 4; ++gi) {
            const _Float16* vp =
                Vt + (size_t)(b * 16 + wave * 4 + gi) * 65536 + t0 + quad * 8;
            #pragma unroll
            for (int dm = 0; dm < 4; ++dm)
                vv[gi][dm] = *(const h8_t*)(vp + (size_t)(dm * 16 + l15) * 1024);
        }
        // ---- Phase C: O^T[d][q] += V^T[d][t] * P^T[t][q]   (P wave-private)
        #pragma unroll
        for (int gi = 0; gi < 4; ++gi) {
            h8_t bp = *(const h8_t*)&P_lds[wave * 4 + gi][l15][quad * 8];
            #pragma unroll
            for (int dm = 0; dm < 4; ++dm)
                acc[gi][dm] = MFMA16(vv[gi][dm], bp, acc[gi][dm]);
        }
        __syncthreads(); // all R reads done before next iter's Phase A overwrites
    }

    // ---- epilogue: write unnormalized partial O^T and per-row (m, l)
    float* op = kz ? out1 : out0;
    #pragma unroll
    for (int gi = 0; gi < 4; ++gi) {
        int g = wave * 4 + gi;
        #pragma unroll
        for (int dm = 0; dm < 4; ++dm) {
            float* p = op + ((size_t)b * 1024 + q0 + l15) * 1024 + g * 64 + dm * 16 + quad * 4;
            *(f4_t*)p = acc[gi][dm];
        }
        if (quad == 0) {
            size_t mi = (((size_t)kz * 8 + b) * 16 + g) * 1024 + q0 + l15;
            mpart[mi] = mst[gi];
            lpart[mi] = lst[gi];
        }
    }
}

// ---------------------------------------------------------------------------
// Merge the two split-K halves: out = (O0*w0 + O1*w1) / (l0*w0 + l1*w1),
// w_z = exp(m_z - max(m0,m1)). One f4 of the output per thread.
__global__ void combine_kernel(const float* __restrict__ part1,
                               const float* __restrict__ mpart,
                               const float* __restrict__ lpart,
                               float* __restrict__ out, int n4) {
    int i = blockIdx.x * 256 + threadIdx.x;
    if (i >= n4) return;
    const int ZS = 8 * 16 * 1024; // per-z m/l stride
    int h = (i >> 4) & 15;
    int q = (i >> 8) & 1023;
    int b = i >> 18;
    size_t mi = ((size_t)b * 16 + h) * 1024 + q;
    float m0 = mpart[mi], l0 = lpart[mi];
    float m1 = mpart[mi + ZS], l1 = lpart[mi + ZS];
    float M = fmaxf(m0, m1);
    float w0 = __expf(m0 - M), w1 = __expf(m1 - M);
    float inv = 1.0f / (l0 * w0 + l1 * w1);
    f4_t o0 = *(const f4_t*)(out + (size_t)i * 4);
    f4_t o1 = *(const f4_t*)(part1 + (size_t)i * 4);
    f4_t r = (o0 * w0 + o1 * w1) * inv;
    *(f4_t*)(out + (size_t)i * 4) = r;
}

// ---------------------------------------------------------------------------
extern "C" void kernel_launch(void* const* d_in, const int* in_sizes, int n_in,
                              void* d_out, int out_size, void* d_ws, size_t ws_size,
                              hipStream_t stream) {
    const float* q    = (const float*)d_in[0];
    const float* k    = (const float*)d_in[1];
    const float* v    = (const float*)d_in[2];
    const float* rel  = (const float*)d_in[3];
    const float* Wq   = (const float*)d_in[4];
    const float* bq   = (const float*)d_in[5];
    const float* Wk   = (const float*)d_in[6];
    const float* bk   = (const float*)d_in[7];
    const float* Wv   = (const float*)d_in[8];
    const float* bv   = (const float*)d_in[9];
    const int*   mask = (const int*)d_in[10];
    float* out = (float*)d_out;

    const size_t NEL = 8ull * 1024 * 1024;      // activation elements
    const size_t WEL = 1024ull * 1024;          // weight elements

    char* w = (char*)d_ws;
    size_t off = 0;
    auto alloc = [&](size_t bytes) { char* p = w + off; off += bytes; return p; };
    _Float16* Wqt = (_Float16*)alloc(WEL * 2);
    _Float16* Wkt = (_Float16*)alloc(WEL * 2);
    _Float16* Wvt = (_Float16*)alloc(WEL * 2);
    _Float16* Qh  = (_Float16*)alloc(NEL * 2);
    _Float16* Kh  = (_Float16*)alloc(NEL * 2);
    _Float16* Vth = (_Float16*)alloc(NEL * 2);
    float* part1 = (float*)alloc(NEL * 4);           // 33.55 MB
    float* mpart = (float*)alloc(2ull * 8 * 16 * 1024 * 4);
    float* lpart = (float*)alloc(2ull * 8 * 16 * 1024 * 4);
    // total ~89.6 MB — fits the proven workspace budget

    dim3 tg(32, 32);
    wtrans<<<tg, 256, 0, stream>>>(Wq, Wqt);
    wtrans<<<tg, 256, 0, stream>>>(Wk, Wkt);
    wtrans<<<tg, 256, 0, stream>>>(Wv, Wvt);

    dim3 pg(64, 8);
    proj_gemm<<<pg, 256, 0, stream>>>(q, Wqt, bq, Qh, 1.0f, 0);
    proj_gemm<<<pg, 256, 0, stream>>>(k, Wkt, bk, Kh, 0.125f, 0); // fold 1/sqrt(dk)
    proj_gemm<<<pg, 256, 0, stream>>>(v, Wvt, bv, Vth, 1.0f, 1);  // V transposed

    dim3 ag(64, 8, 2);
    attn_kernel<<<ag, 256, 0, stream>>>(Qh, Kh, Vth, rel, mask, out, part1, mpart, lpart);

    int n4 = (int)(NEL / 4);
    combine_kernel<<<(n4 + 255) / 256, 256, 0, stream>>>(part1, mpart, lpart, out, n4);
}

// Round 3
// 1064.914 us; speedup vs baseline: 1.2590x; 1.2590x over previous
//
#include <hip/hip_runtime.h>

typedef _Float16 h8_t __attribute__((ext_vector_type(8)));
typedef _Float16 h4_t __attribute__((ext_vector_type(4)));
typedef float f4_t __attribute__((ext_vector_type(4)));

#define MFMA16(a, b, c) __builtin_amdgcn_mfma_f32_16x16x32_f16((a), (b), (c), 0, 0, 0)

// async global->LDS DMA, 16B per lane; LDS dest must be wave-uniform base + lane*16
__device__ inline void gl_lds16(const _Float16* g, _Float16* l) {
    __builtin_amdgcn_global_load_lds(
        (const __attribute__((address_space(1))) unsigned int*)g,
        (__attribute__((address_space(3))) unsigned int*)l, 16, 0, 0);
}

// ---------------------------------------------------------------------------
// W [K=1024][N=1024] f32 -> Wt [N][K] f16, 3 weights in one launch (z selects)
__global__ void wtrans3(const float* __restrict__ W0, const float* __restrict__ W1,
                        const float* __restrict__ W2, _Float16* __restrict__ T0,
                        _Float16* __restrict__ T1, _Float16* __restrict__ T2) {
    __shared__ float tile[32][33];
    const int z = blockIdx.z;
    const float* W = z == 0 ? W0 : (z == 1 ? W1 : W2);
    _Float16* Wt = z == 0 ? T0 : (z == 1 ? T1 : T2);
    int tid = threadIdx.x;
    int tx = tid & 31, ty = tid >> 5;
    int nb = blockIdx.x * 32, kb = blockIdx.y * 32;
    for (int p = 0; p < 4; ++p)
        tile[ty + p * 8][tx] = W[(size_t)(kb + ty + p * 8) * 1024 + nb + tx];
    __syncthreads();
    for (int p = 0; p < 4; ++p)
        Wt[(size_t)(nb + ty + p * 8) * 1024 + kb + tx] = (_Float16)tile[tx][ty + p * 8];
}

// ---------------------------------------------------------------------------
// All three projection GEMMs in ONE launch: grid (64, 8, 3); z selects
// {X, Wt, bias, Out, scale, vmode}. 1536 blocks -> ~4 WGs/CU co-resident
// (vs 3x512 = 2 WGs/CU grid-capped). A-operand read from f32 (reg-stage +
// cvt), B-operand staged via global_load_lds.
// vmode==0: Out [b][h][s][64] ; vmode==1: Out [b][h][64][s] (V transposed)
__global__ __launch_bounds__(256, 2) void proj_gemm3(
    const float* __restrict__ X0, const float* __restrict__ X1,
    const float* __restrict__ X2, const _Float16* __restrict__ W0,
    const _Float16* __restrict__ W1, const _Float16* __restrict__ W2,
    const float* __restrict__ b0, const float* __restrict__ b1,
    const float* __restrict__ b2, _Float16* __restrict__ O0,
    _Float16* __restrict__ O1, _Float16* __restrict__ O2)
{
    __shared__ __align__(16) _Float16 Asm[128 * 32];
    __shared__ __align__(16) _Float16 Bsm[128 * 32];
    const int z = blockIdx.z;
    const float* X = z == 0 ? X0 : (z == 1 ? X1 : X2);
    const _Float16* Wt = z == 0 ? W0 : (z == 1 ? W1 : W2);
    const float* bias = z == 0 ? b0 : (z == 1 ? b1 : b2);
    _Float16* Out = z == 0 ? O0 : (z == 1 ? O1 : O2);
    const float scale = (z == 1) ? 0.125f : 1.0f;  // fold 1/sqrt(dk) into K
    const int vmode = (z == 2);

    int tid = threadIdx.x;
    int wave = tid >> 6, lane = tid & 63;
    int l15 = lane & 15, quad = lane >> 4;
    int m0 = blockIdx.x * 128, n0 = blockIdx.y * 128;
    int wm = (wave >> 1) * 64, wn = (wave & 1) * 64;
    f4_t acc[4][4] = {};
    int f0 = wave * 128 + lane;

    for (int kt = 0; kt < 1024; kt += 32) {
        #pragma unroll
        for (int j = 0; j < 2; ++j) {
            int f = f0 + j * 64;
            int r = f >> 2, c = (f & 3) * 8;
            gl_lds16(&Wt[(size_t)(n0 + r) * 1024 + kt + c], &Bsm[f * 8]);
        }
        #pragma unroll
        for (int j = 0; j < 2; ++j) {
            int f = f0 + j * 64;
            int r = f >> 2, c = (f & 3) * 8;
            const float* xp = &X[(size_t)(m0 + r) * 1024 + kt + c];
            f4_t x0 = *(const f4_t*)xp;
            f4_t x1 = *(const f4_t*)(xp + 4);
            h8_t h;
            #pragma unroll
            for (int i = 0; i < 4; ++i) { h[i] = (_Float16)x0[i]; h[4 + i] = (_Float16)x1[i]; }
            *(h8_t*)&Asm[f * 8] = h;
        }
        __syncthreads();  // drains vmcnt(0) (B staging) + lgkm (A ds_writes)
        h8_t af[4], bf[4];
        #pragma unroll
        for (int i = 0; i < 4; ++i) af[i] = *(const h8_t*)&Asm[(wm + i * 16 + l15) * 32 + quad * 8];
        #pragma unroll
        for (int j = 0; j < 4; ++j) bf[j] = *(const h8_t*)&Bsm[(wn + j * 16 + l15) * 32 + quad * 8];
        #pragma unroll
        for (int i = 0; i < 4; ++i)
            #pragma unroll
            for (int j = 0; j < 4; ++j)
                acc[i][j] = MFMA16(af[i], bf[j], acc[i][j]);
        __syncthreads();
    }
    #pragma unroll
    for (int j = 0; j < 4; ++j) {
        int n = n0 + wn + j * 16 + l15;
        float bv = bias[n];
        int h = n >> 6, d = n & 63;
        #pragma unroll
        for (int i = 0; i < 4; ++i) {
            #pragma unroll
            for (int r = 0; r < 4; ++r) {
                int m = m0 + wm + i * 16 + quad * 4 + r;
                int bb = m >> 10, ss = m & 1023;
                float v = (acc[i][j][r] + bv) * scale;
                size_t oidx = vmode ? (((size_t)(bb * 16 + h) * 64 + d) * 1024 + ss)
                                    : (((size_t)(bb * 16 + h) * 1024 + ss) * 64 + d);
                Out[oidx] = (_Float16)v;
            }
        }
    }
}

// ---------------------------------------------------------------------------
// rel B-operand loader, f32 -> h8 fragment
__device__ inline h8_t ld_rel32(const float* __restrict__ relf, size_t idx) {
    f4_t a = *(const f4_t*)(relf + idx);
    f4_t b = *(const f4_t*)(relf + idx + 4);
    h8_t h;
    #pragma unroll
    for (int j = 0; j < 4; ++j) { h[j] = (_Float16)a[j]; h[4 + j] = (_Float16)b[j]; }
    return h;
}

// ---------------------------------------------------------------------------
// Fused attention, split-K flash style. Grid (64 q-blocks, 8 batches, 2 k-halves).
// Each WG: 16 q-rows x all 16 heads x 512 keys; writes UNNORMALIZED partial
// O^T + per-row (m, l). combine_kernel merges the two halves.
// Round-0 proven structure: scores transposed D[t][q] (softmax rows in lane
// dim l15=q), Kh pre-scaled 1/8, rel added unscaled.
// LDS = 19584 (R, single-buffered) + 20480 (P, wave-private) = 40064 B
// -> 4 WGs/CU by LDS. launch_bounds(256,2): round-0-proven codegen (124 VGPR,
// zero spills) — hardware occupancy comes from actual usage (124<=128 ->
// 4 waves/EU), NOT from the bound. (256,4) made the allocator cap at 64 VGPR
// and spill ~790 MB/dispatch — round-2 lesson.
__global__ __launch_bounds__(256, 2) void attn_kernel(
    const _Float16* __restrict__ Qh,   // [B][H][S][64]
    const _Float16* __restrict__ Kh,   // [B][H][S][64], pre-scaled 1/8
    const _Float16* __restrict__ Vt,   // [B][H][64][S]
    const float* __restrict__ relf,    // [S][S][64] f32
    const int* __restrict__ mask,      // [B][S][S] int32 (nonzero = masked)
    float* __restrict__ out0,          // z=0 partial (final out buffer)
    float* __restrict__ out1,          // z=1 partial (workspace)
    float* __restrict__ mpart,         // [2][B][H][S]
    float* __restrict__ lpart)         // [2][B][H][S]
{
    __shared__ __align__(16) _Float16 R_lds[16][17][36]; // [q_local][g][t]
    __shared__ __align__(16) _Float16 P_lds[16][16][40]; // [g][q_local][t] (wave-private)

    const int tid = threadIdx.x;
    const int wave = tid >> 6, lane = tid & 63;
    const int l15 = lane & 15, quad = lane >> 4;
    const int b = blockIdx.y;
    const int q0 = blockIdx.x * 16;
    const int kz = blockIdx.z;
    const int tbase = kz * 512;

    // persistent B-operand fragments of Q
    h8_t bQ[4][2]; // QK: B[d][q] for wave's 4 heads g
    h8_t bR[4][2]; // rel: B[d][g] for wave's 4 queries q
    #pragma unroll
    for (int gi = 0; gi < 4; ++gi) {
        int g = wave * 4 + gi;
        const _Float16* qp = Qh + ((size_t)(b * 16 + g) * 1024 + q0 + l15) * 64 + quad * 8;
        bQ[gi][0] = *(const h8_t*)qp;
        bQ[gi][1] = *(const h8_t*)(qp + 32);
    }
    #pragma unroll
    for (int qi = 0; qi < 4; ++qi) {
        int q = q0 + wave * 4 + qi;
        const _Float16* qp = Qh + ((size_t)(b * 16 + l15) * 1024 + q) * 64 + quad * 8;
        bR[qi][0] = *(const h8_t*)qp;
        bR[qi][1] = *(const h8_t*)(qp + 32);
    }

    f4_t acc[4][4] = {}; // [gi][dm] O^T frags: rows d, cols q
    float mst[4], lst[4];
    #pragma unroll
    for (int gi = 0; gi < 4; ++gi) { mst[gi] = -1e30f; lst[gi] = 0.0f; }

    for (int it = 0; it < 16; ++it) {
        const int t0 = tbase + it * 32;

        // mask bits for this lane's q row (independent — issue first)
        const int* mrow = &mask[((size_t)b * 1024 + q0 + l15) * 1024 + t0];
        int4 mk0 = *(const int4*)(mrow + quad * 4);
        int4 mk1 = *(const int4*)(mrow + 16 + quad * 4);

        // ---- rel batch: 16 independent 32B streams issued before any consumer
        h8_t relv[4][2][2];
        #pragma unroll
        for (int qi = 0; qi < 4; ++qi) {
            size_t rb = ((size_t)(q0 + wave * 4 + qi) * 1024 + t0 + l15) * 64 + quad * 8;
            relv[qi][0][0] = ld_rel32(relf, rb);
            relv[qi][0][1] = ld_rel32(relf, rb + 32);
            relv[qi][1][0] = ld_rel32(relf, rb + 1024);
            relv[qi][1][1] = ld_rel32(relf, rb + 1056);
        }
        // ---- Phase A: rel GEMMs, D[t][g] per owned q -> R_lds
        #pragma unroll
        for (int qi = 0; qi < 4; ++qi) {
            #pragma unroll
            for (int tm = 0; tm < 2; ++tm) {
                f4_t c = {0.f, 0.f, 0.f, 0.f};
                c = MFMA16(relv[qi][tm][0], bR[qi][0], c);
                c = MFMA16(relv[qi][tm][1], bR[qi][1], c);
                h4_t h;
                #pragma unroll
                for (int r = 0; r < 4; ++r) h[r] = (_Float16)c[r];
                *(h4_t*)&R_lds[wave * 4 + qi][l15][tm * 16 + quad * 4] = h;
            }
        }

        // ---- K batch: issued pre-barrier so latency drains during barrier
        h8_t kv[4][2][2];
        #pragma unroll
        for (int gi = 0; gi < 4; ++gi) {
            const _Float16* kp =
                Kh + ((size_t)(b * 16 + wave * 4 + gi) * 1024 + t0 + l15) * 64 + quad * 8;
            kv[gi][0][0] = *(const h8_t*)kp;
            kv[gi][0][1] = *(const h8_t*)(kp + 32);
            kv[gi][1][0] = *(const h8_t*)(kp + 1024);
            kv[gi][1][1] = *(const h8_t*)(kp + 1056);
        }
        __syncthreads(); // R_lds visible to all waves

        int mm[8] = {mk0.x, mk0.y, mk0.z, mk0.w, mk1.x, mk1.y, mk1.z, mk1.w};

        // ---- Phase B: QK^T (transposed) + online softmax, all in registers
        #pragma unroll
        for (int gi = 0; gi < 4; ++gi) {
            int g = wave * 4 + gi;
            f4_t s[2];
            #pragma unroll
            for (int tm = 0; tm < 2; ++tm) {
                h4_t rh = *(const h4_t*)&R_lds[l15][g][tm * 16 + quad * 4];
                f4_t c;
                #pragma unroll
                for (int r = 0; r < 4; ++r) c[r] = (float)rh[r];
                c = MFMA16(kv[gi][tm][0], bQ[gi][0], c);
                c = MFMA16(kv[gi][tm][1], bQ[gi][1], c);
                s[tm] = c;
            }
            #pragma unroll
            for (int tm = 0; tm < 2; ++tm)
                #pragma unroll
                for (int r = 0; r < 4; ++r)
                    if (mm[tm * 4 + r]) s[tm][r] = -1e8f;

            float mx = s[0][0];
            #pragma unroll
            for (int tm = 0; tm < 2; ++tm)
                #pragma unroll
                for (int r = 0; r < 4; ++r) mx = fmaxf(mx, s[tm][r]);
            mx = fmaxf(mx, __shfl_xor(mx, 16));
            mx = fmaxf(mx, __shfl_xor(mx, 32));
            float mnew = fmaxf(mst[gi], mx);
            float alpha = __expf(mst[gi] - mnew);
            mst[gi] = mnew;
            float rs = 0.0f;
            #pragma unroll
            for (int tm = 0; tm < 2; ++tm)
                #pragma unroll
                for (int r = 0; r < 4; ++r) {
                    float p = __expf(s[tm][r] - mnew);
                    s[tm][r] = p;
                    rs += p;
                }
            rs += __shfl_xor(rs, 16);
            rs += __shfl_xor(rs, 32);
            lst[gi] = lst[gi] * alpha + rs;
            #pragma unroll
            for (int dm = 0; dm < 4; ++dm) acc[gi][dm] *= alpha; // alpha uniform per lane (q=l15)
            #pragma unroll
            for (int tm = 0; tm < 2; ++tm) {
                h4_t h;
                #pragma unroll
                for (int r = 0; r < 4; ++r) h[r] = (_Float16)s[tm][r];
                *(h4_t*)&P_lds[g][l15][tm * 16 + quad * 4] = h;
            }
        }

        // ---- V batch (kv regs dead by now)
        h8_t vv[4][4];
        #pragma unroll
        for (int gi = 0; gi < 4; ++gi) {
            const _Float16* vp =
                Vt + (size_t)(b * 16 + wave * 4 + gi) * 65536 + t0 + quad * 8;
            #pragma unroll
            for (int dm = 0; dm < 4; ++dm)
                vv[gi][dm] = *(const h8_t*)(vp + (size_t)(dm * 16 + l15) * 1024);
        }
        // ---- Phase C: O^T[d][q] += V^T[d][t] * P^T[t][q]   (P wave-private)
        #pragma unroll
        for (int gi = 0; gi < 4; ++gi) {
            h8_t bp = *(const h8_t*)&P_lds[wave * 4 + gi][l15][quad * 8];
            #pragma unroll
            for (int dm = 0; dm < 4; ++dm)
                acc[gi][dm] = MFMA16(vv[gi][dm], bp, acc[gi][dm]);
        }
        __syncthreads(); // all R reads done before next iter's Phase A overwrites
    }

    // ---- epilogue: write unnormalized partial O^T and per-row (m, l)
    float* op = kz ? out1 : out0;
    #pragma unroll
    for (int gi = 0; gi < 4; ++gi) {
        int g = wave * 4 + gi;
        #pragma unroll
        for (int dm = 0; dm < 4; ++dm) {
            float* p = op + ((size_t)b * 1024 + q0 + l15) * 1024 + g * 64 + dm * 16 + quad * 4;
            *(f4_t*)p = acc[gi][dm];
        }
        if (quad == 0) {
            size_t mi = (((size_t)kz * 8 + b) * 16 + g) * 1024 + q0 + l15;
            mpart[mi] = mst[gi];
            lpart[mi] = lst[gi];
        }
    }
}

// ---------------------------------------------------------------------------
// Merge the two split-K halves: out = (O0*w0 + O1*w1) / (l0*w0 + l1*w1),
// w_z = exp(m_z - max(m0,m1)). One f4 of the output per thread.
__global__ void combine_kernel(const float* __restrict__ part1,
                               const float* __restrict__ mpart,
                               const float* __restrict__ lpart,
                               float* __restrict__ out, int n4) {
    int i = blockIdx.x * 256 + threadIdx.x;
    if (i >= n4) return;
    const int ZS = 8 * 16 * 1024; // per-z m/l stride
    int h = (i >> 4) & 15;
    int q = (i >> 8) & 1023;
    int b = i >> 18;
    size_t mi = ((size_t)b * 16 + h) * 1024 + q;
    float m0 = mpart[mi], l0 = lpart[mi];
    float m1 = mpart[mi + ZS], l1 = lpart[mi + ZS];
    float M = fmaxf(m0, m1);
    float w0 = __expf(m0 - M), w1 = __expf(m1 - M);
    float inv = 1.0f / (l0 * w0 + l1 * w1);
    f4_t o0 = *(const f4_t*)(out + (size_t)i * 4);
    f4_t o1 = *(const f4_t*)(part1 + (size_t)i * 4);
    f4_t r = (o0 * w0 + o1 * w1) * inv;
    *(f4_t*)(out + (size_t)i * 4) = r;
}

// ---------------------------------------------------------------------------
extern "C" void kernel_launch(void* const* d_in, const int* in_sizes, int n_in,
                              void* d_out, int out_size, void* d_ws, size_t ws_size,
                              hipStream_t stream) {
    const float* q    = (const float*)d_in[0];
    const float* k    = (const float*)d_in[1];
    const float* v    = (const float*)d_in[2];
    const float* rel  = (const float*)d_in[3];
    const float* Wq   = (const float*)d_in[4];
    const float* bq   = (const float*)d_in[5];
    const float* Wk   = (const float*)d_in[6];
    const float* bk   = (const float*)d_in[7];
    const float* Wv   = (const float*)d_in[8];
    const float* bv   = (const float*)d_in[9];
    const int*   mask = (const int*)d_in[10];
    float* out = (float*)d_out;

    const size_t NEL = 8ull * 1024 * 1024;      // activation elements
    const size_t WEL = 1024ull * 1024;          // weight elements

    char* w = (char*)d_ws;
    size_t off = 0;
    auto alloc = [&](size_t bytes) { char* p = w + off; off += bytes; return p; };
    _Float16* Wqt = (_Float16*)alloc(WEL * 2);
    _Float16* Wkt = (_Float16*)alloc(WEL * 2);
    _Float16* Wvt = (_Float16*)alloc(WEL * 2);
    _Float16* Qh  = (_Float16*)alloc(NEL * 2);
    _Float16* Kh  = (_Float16*)alloc(NEL * 2);
    _Float16* Vth = (_Float16*)alloc(NEL * 2);
    float* part1 = (float*)alloc(NEL * 4);           // 33.55 MB
    float* mpart = (float*)alloc(2ull * 8 * 16 * 1024 * 4);
    float* lpart = (float*)alloc(2ull * 8 * 16 * 1024 * 4);
    // total ~89.6 MB — fits the proven workspace budget

    dim3 tg(32, 32, 3);
    wtrans3<<<tg, 256, 0, stream>>>(Wq, Wk, Wv, Wqt, Wkt, Wvt);

    dim3 pg(64, 8, 3);
    proj_gemm3<<<pg, 256, 0, stream>>>(q, k, v, Wqt, Wkt, Wvt, bq, bk, bv, Qh, Kh, Vth);

    dim3 ag(64, 8, 2);
    attn_kernel<<<ag, 256, 0, stream>>>(Qh, Kh, Vth, rel, mask, out, part1, mpart, lpart);

    int n4 = (int)(NEL / 4);
    combine_kernel<<<(n4 + 255) / 256, 256, 0, stream>>>(part1, mpart, lpart, out, n4);
}